// Round 1
// 251.592 us; speedup vs baseline: 1.1396x; 1.1396x over previous
//
#include <hip/hip_runtime.h>
#include <math.h>

#define B 1024
#define T 512
#define S 48
#define SOS 47

// broadcast lane l's value to all lanes via the SGPR file
__device__ __forceinline__ float rdlanef(float v, int l) {
    return __int_as_float(__builtin_amdgcn_readlane(__float_as_int(v), l));
}

// ---------------------------------------------------------------------------
// Fused CRF loss. One wave per row; lane i owns state i; expT row in VGPRs.
// Scan kept in exp space with DELAYED normalization:
//   invariant  u_t = q * exp(M)   (exact; r_s == exp(-l_s) pending factor)
//   live step: q' = (expT q) * exp(emis - er) * r_s ;  M += er + l_s
//              then r_s = rcp(d1), l_s = log(d1)   [off critical chain]
//
// ROUND 1 (this session): q-broadcast moved from LDS to v_readlane->SGPR.
// The old chain paid ds_write + 12x ds_read_b128 per step: each broadcast
// read returns 64 lanes x 16B = 1KB on the DS return bus (>=8-16 cyc DS-pipe
// occupancy each, in order, ON the serial chain) plus ~120 cyc latency.
// v_readlane puts q_j in an SGPR; v_fmac reads it through the scalar operand
// network (broadcast is free at consume time). 48 readlanes are plain VALU
// ops, 2 cyc issue, ~4 cyc latency, fully pipelined; the chain becomes pure
// VALU and the DS pipe disappears from the kernel entirely.
// Dot math is BITWISE IDENTICAL to the previous passing kernel: same
// 4-accumulator split (ax: j%4==0, ay: j%4==1, ...), same summation order,
// same er shift, same per-step normalization schedule.
// Emission/mask prefetch double-buffered per 8-step block so vmem waits only
// ever hit loads aged by a full block. amdgpu_waves_per_eu(1): full VGPR
// budget; occupancy is structurally 1 wave/SIMD (1024 single-wave blocks).
// ---------------------------------------------------------------------------
__global__ __launch_bounds__(64, 1)
__attribute__((amdgpu_waves_per_eu(1)))
void crf_fused(const float* __restrict__ feat,
               const int* __restrict__ states,
               const float* __restrict__ mask,
               const float* __restrict__ trans,
               float* __restrict__ out) {
    const int b = blockIdx.x;
    const int lane = threadIdx.x;
    const int elane = (lane < S) ? lane : 0;    // lanes 48-63 shadow lane 0
    const float* f_b = feat + (size_t)b * T * S;
    const float* m_b = mask + b * T;
    const int* st_b = states + b * T;

    // ---- numerator (latency overlaps expT setup) ----
    float nsum = 0.f;
#pragma unroll
    for (int k2 = 0; k2 < T / 64; ++k2) {
        const int t = lane + k2 * 64;
        const int st = st_b[t];
        const int pv = (t == 0) ? SOS : st_b[t - 1];
        nsum += (f_b[t * S + st] + trans[st * S + pv]) * m_b[t];
    }

    // ---- expT row for this lane; exp(-9999) underflows to exact 0 ----
    float expT[S];
    {
        const float4* t4 = (const float4*)(trans + elane * S);
#pragma unroll
        for (int j4 = 0; j4 < S / 4; ++j4) {
            const float4 tv = t4[j4];
            expT[4 * j4 + 0] = (lane < S) ? __expf(tv.x) : 0.f;
            expT[4 * j4 + 1] = (lane < S) ? __expf(tv.y) : 0.f;
            expT[4 * j4 + 2] = (lane < S) ? __expf(tv.z) : 0.f;
            expT[4 * j4 + 3] = (lane < S) ? __expf(tv.w) : 0.f;
        }
    }

    // ---- scan state ----
    float q = (lane == SOS) ? 1.f : 0.f;        // lanes >= 48 hold 0 forever
    float M = 0.f;
    float r_s = 1.f, l_s = 0.f;      // pending normalizer: r_s == exp(-l_s)

    // emission/mask double-buffered block rings (8 steps per block)
    float ering[2][8], mring[2][8];
#pragma unroll
    for (int k = 0; k < 8; ++k) {
        ering[0][k] = f_b[k * S + elane];
        mring[0][k] = m_b[k];
    }

#pragma unroll 2
    for (int tb = 0; tb < T / 8; ++tb) {
        const int pb = tb & 1;
        // issue next block's loads now; consumed a full block later
        const int tn = ((tb + 1) & (T / 8 - 1)) * 8;   // wrap: last refill unused
#pragma unroll
        for (int k = 0; k < 8; ++k) {
            ering[pb ^ 1][k] = f_b[(tn + k) * S + elane];
            mring[pb ^ 1][k] = m_b[tn + k];
        }
#pragma unroll
        for (int k = 0; k < 8; ++k) {
            // off-chain: per-lane factor from prefetched emission
            const float emis = ering[pb][k];
            const float er = rdlanef(emis, 1);
            const float F = __expf(emis - er) * r_s;
            // chain: SGPR-broadcast dot d_i = expT[i] . q
            // (48 v_readlane + 48 v_fmac; bitwise-identical accumulation
            //  order to the LDS float4 version)
            float ax = 0.f, ay = 0.f, az = 0.f, aw = 0.f;
#pragma unroll
            for (int j4 = 0; j4 < S / 4; ++j4) {
                ax = fmaf(expT[4 * j4 + 0], rdlanef(q, 4 * j4 + 0), ax);
                ay = fmaf(expT[4 * j4 + 1], rdlanef(q, 4 * j4 + 1), ay);
                az = fmaf(expT[4 * j4 + 2], rdlanef(q, 4 * j4 + 2), az);
                aw = fmaf(expT[4 * j4 + 3], rdlanef(q, 4 * j4 + 3), aw);
            }
            const float d = (ax + ay) + (az + aw);
            const float qn = d * F;
            const bool live = (mring[pb][k] != 0.f);
            q = live ? qn : q;                  // SELECT, never blend
            // off-chain: next normalizer + shift bookkeeping
            M = live ? (M + er + l_s) : M;      // uses OLD l_s, then update
            const float dr = rdlanef(d, 1);     // lane1 dot: provably > 0
            const float nl = __logf(dr);
            const float nr = __builtin_amdgcn_rcpf(dr);
            r_s = live ? nr : r_s;
            l_s = live ? nl : l_s;
        }
    }

    // ---- epilogue: denom = M + log(sum_i q_i); out = denom - numer ----
    float ps = q;                               // lanes >= 48 hold 0
#pragma unroll
    for (int off = 32; off > 0; off >>= 1) {
        ps += __shfl_xor(ps, off, 64);
        nsum += __shfl_xor(nsum, off, 64);
    }
    if (lane == 0) out[b] = M + __logf(ps) - nsum;
}

extern "C" void kernel_launch(void* const* d_in, const int* in_sizes, int n_in,
                              void* d_out, int out_size, void* d_ws, size_t ws_size,
                              hipStream_t stream) {
    const float* feat   = (const float*)d_in[0];   // (B,T,S) f32
    const int*   states = (const int*)d_in[1];     // (B,T) i32
    const float* mask   = (const float*)d_in[2];   // (B,T) f32
    const float* trans  = (const float*)d_in[3];   // (S,S) f32
    float* out = (float*)d_out;                    // (B,) f32

    crf_fused<<<dim3(B), dim3(64), 0, stream>>>(feat, states, mask, trans, out);
}